// Round 3
// baseline (5451.567 us; speedup 1.0000x reference)
//
#include <hip/hip_runtime.h>
#include <math.h>

// Problem constants (fixed by reference).
#define HIDDEN 1024
#define MEL    80
#define TSTEPS 1000
#define BATCH  64

// Recurrence geometry: 64 persistent blocks (all co-resident on 256 CUs),
// each owns 16 hidden units = 64 gate rows; 8 threads per gate row.
#define NBLK 64
#define TPB  512
#define JPB  16                 // hidden units per block
#define ROWS 64                 // gate rows per block
#define CPT  128                // columns per thread (HIDDEN/8)

typedef unsigned long long ull;

// v_exp_f32-based fast activations (abs err ~1e-6, threshold is 8.3e-4).
__device__ __forceinline__ float sigm_f(float x) { return 1.0f / (1.0f + __expf(-x)); }
__device__ __forceinline__ float tanh_f(float x) { return 1.0f - 2.0f / (1.0f + __expf(2.0f * x)); }
// saturates correctly: x>>0 -> exp=inf -> 1; x<<0 -> exp=0 -> -1.

// Logical h index -> physical LDS float index. Per-c8 rotation so each wave's
// 8 unique float4 reads cover all 32 banks AND the MAC loop's ds_read_b128
// stream uses pure immediate offsets (no per-read address VALU).
__device__ __forceinline__ int hperm(int i) {
    const int c8 = i >> 7, c4 = (i >> 2) & 31, w = i & 3;
    return (((c8 << 5) | ((c4 - c8) & 31)) << 2) | w;
}

// Persistent decoder recurrence. Weights folded (W_comb = Whh + Wih@lin_W)
// into registers (fp32). Cross-block exchange: hbuf[2][1024] of packed
// {tag:32 | float:32} via L2-bypassing (system-scope relaxed) atomics.
// No fences, no barrier counter, no buffer_wbl2/inv in the loop.
__global__ __launch_bounds__(TPB, 2) void tts_recur(
    const float* __restrict__ dec_Wih,   // [4096, 80]
    const float* __restrict__ dec_Whh,   // [4096, 1024]
    const float* __restrict__ dec_bih,   // [4096]
    const float* __restrict__ dec_bhh,   // [4096]
    const float* __restrict__ lin_W,     // [80, 1024]
    const float* __restrict__ lin_b,     // [80]
    float* __restrict__ h_hist,          // [TSTEPS, 1024] (cached, for epilogue)
    ull* __restrict__ hbuf)              // [2, 1024] packed exchange
{
    const int tid  = threadIdx.x;
    const int blk  = blockIdx.x;
    const int r    = tid >> 3;           // gate row 0..63
    const int c8   = tid & 7;            // column chunk 0..7
    const int gate = r >> 4;             // i,f,g,o
    const int jj   = r & (JPB - 1);
    const int row_g = gate * HIDDEN + blk * JPB + jj;

    __shared__ __align__(16) float h_s[HIDDEN];
    __shared__ float g_s[ROWS];
    __shared__ float c_s[JPB];

    // ---- one-time fold: w[k] = Whh_row + Wih_row @ lin_W (fp32, registers) ----
    const float* wih = dec_Wih + (size_t)row_g * MEL;
    const float* whh = dec_Whh + (size_t)row_g * HIDDEN;
    float4 w[32];
#pragma unroll
    for (int k = 0; k < 32; ++k) {
        const int c4  = (k + c8) & 31;
        const int col = c8 * CPT + c4 * 4;
        float4 a = *(const float4*)(whh + col);
        for (int m = 0; m < MEL; ++m) {
            const float aw = wih[m];
            const float4 lw = *(const float4*)(lin_W + (size_t)m * HIDDEN + col);
            a.x = fmaf(aw, lw.x, a.x);
            a.y = fmaf(aw, lw.y, a.y);
            a.z = fmaf(aw, lw.z, a.z);
            a.w = fmaf(aw, lw.w, a.w);
        }
        w[k] = a;
    }
    const float b_dec_r = dec_bih[row_g] + dec_bhh[row_g];
    float b_comb_r = b_dec_r;
    for (int m = 0; m < MEL; ++m)
        b_comb_r = fmaf(wih[m], lin_b[m], b_comb_r);

    // ---- step 0: g = b_dec (h=c=x=0) ----
    if (c8 == 0) g_s[r] = b_dec_r;
    __syncthreads();
    if (tid < JPB) {
        const float gi = g_s[tid], gg = g_s[2 * JPB + tid], go = g_s[3 * JPB + tid];
        const float c = sigm_f(gi) * tanh_f(gg);    // f-gate * c0 = 0
        const float h = sigm_f(go) * tanh_f(c);
        c_s[tid] = c;
        const ull pk = ((ull)1u << 32) | (ull)__float_as_uint(h);
        __hip_atomic_store(hbuf + blk * JPB + tid, pk,
                           __ATOMIC_RELAXED, __HIP_MEMORY_SCOPE_SYSTEM);
        h_hist[blk * JPB + tid] = h;
    }

    const int p0 = hperm(tid);
    const int p1 = hperm(tid + 512);

    // ---- steps 1..TSTEPS-1 ----
    for (int t = 1; t < TSTEPS; ++t) {
        // Poll own two slots of h[t-1]; tag==t means value is valid.
        const ull* src = hbuf + ((t - 1) & 1) * HIDDEN;
        const unsigned tag = (unsigned)t;
        ull v;
        do {
            v = __hip_atomic_load(src + tid, __ATOMIC_RELAXED, __HIP_MEMORY_SCOPE_SYSTEM);
        } while ((unsigned)(v >> 32) != tag);
        h_s[p0] = __uint_as_float((unsigned)v);
        do {
            v = __hip_atomic_load(src + tid + 512, __ATOMIC_RELAXED, __HIP_MEMORY_SCOPE_SYSTEM);
        } while ((unsigned)(v >> 32) != tag);
        h_s[p1] = __uint_as_float((unsigned)v);
        __syncthreads();

        // MAC: 32 immediate-offset ds_read_b128 + 128 fma per thread.
        const float4* hs4 = ((const float4*)h_s) + (c8 << 5);
        float acc = 0.0f;
#pragma unroll
        for (int k = 0; k < 32; ++k) {
            const float4 hv = hs4[k];
            acc = fmaf(w[k].x, hv.x, acc);
            acc = fmaf(w[k].y, hv.y, acc);
            acc = fmaf(w[k].z, hv.z, acc);
            acc = fmaf(w[k].w, hv.w, acc);
        }
        acc += __shfl_down(acc, 4, 8);
        acc += __shfl_down(acc, 2, 8);
        acc += __shfl_down(acc, 1, 8);
        if (c8 == 0) g_s[r] = acc + b_comb_r;
        __syncthreads();

        if (tid < JPB) {
            const float gi = g_s[tid], gf = g_s[JPB + tid],
                        gg = g_s[2 * JPB + tid], go = g_s[3 * JPB + tid];
            const float c = sigm_f(gf) * c_s[tid] + sigm_f(gi) * tanh_f(gg);
            const float h = sigm_f(go) * tanh_f(c);
            c_s[tid] = c;
            const ull pk = ((ull)(unsigned)(t + 1) << 32) | (ull)__float_as_uint(h);
            __hip_atomic_store(hbuf + (t & 1) * HIDDEN + blk * JPB + tid, pk,
                               __ATOMIC_RELAXED, __HIP_MEMORY_SCOPE_SYSTEM);
            h_hist[(size_t)t * HIDDEN + blk * JPB + tid] = h;
        }
        // No trailing sync needed: next iteration's post-poll __syncthreads
        // orders h_s/g_s reuse; MAC reads completed before the mid-step sync.
    }
}

// Epilogue: frame[t] = lin_W @ h[t] + lin_b, broadcast to all 64 batch rows.
__global__ __launch_bounds__(128) void tts_frames(
    const float* __restrict__ lin_W, const float* __restrict__ lin_b,
    const float* __restrict__ h_hist, float* __restrict__ out)
{
    const int t = blockIdx.x;
    const int tid = threadIdx.x;
    __shared__ __align__(16) float h_s[HIDDEN];
    const float4* src = (const float4*)(h_hist + (size_t)t * HIDDEN);
    ((float4*)h_s)[tid] = src[tid];
    ((float4*)h_s)[tid + 128] = src[tid + 128];
    __syncthreads();
    if (tid < MEL) {
        const float* wrow = lin_W + (size_t)tid * HIDDEN;
        float acc = lin_b[tid];
#pragma unroll 8
        for (int c = 0; c < HIDDEN; ++c)
            acc = fmaf(wrow[c], h_s[c], acc);
        const size_t o = (size_t)t * MEL + tid;
        for (int b = 0; b < BATCH; ++b)
            out[o + (size_t)b * TSTEPS * MEL] = acc;
    }
}

extern "C" void kernel_launch(void* const* d_in, const int* in_sizes, int n_in,
                              void* d_out, int out_size, void* d_ws, size_t ws_size,
                              hipStream_t stream) {
    // Inputs: 0 text, 1 text_lens, 2 max_audio_len, 3 W_emb, 4..7 enc_*,
    // 8..11 dec_{Wih,Whh,bih,bhh}, 12 lin_W, 13 lin_b. Encoder is dead code.
    const float* dec_Wih = (const float*)d_in[8];
    const float* dec_Whh = (const float*)d_in[9];
    const float* dec_bih = (const float*)d_in[10];
    const float* dec_bhh = (const float*)d_in[11];
    const float* lin_W   = (const float*)d_in[12];
    const float* lin_b   = (const float*)d_in[13];
    float* out = (float*)d_out;

    // Workspace: h_hist fp32 [1000][1024] (4,096,000 B) + hbuf [2][1024] ull.
    // Poisoned 0xAA tags (0xAAAAAAAA) never match tags 1..1000 -> no init pass.
    float* h_hist = (float*)d_ws;
    ull* hbuf = (ull*)((char*)d_ws + (size_t)TSTEPS * HIDDEN * sizeof(float));

    hipLaunchKernelGGL(tts_recur, dim3(NBLK), dim3(TPB), 0, stream,
                       dec_Wih, dec_Whh, dec_bih, dec_bhh, lin_W, lin_b, h_hist, hbuf);
    hipLaunchKernelGGL(tts_frames, dim3(TSTEPS), dim3(128), 0, stream,
                       lin_W, lin_b, h_hist, out);
}

// Round 4
// 5187.313 us; speedup vs baseline: 1.0509x; 1.0509x over previous
//
#include <hip/hip_runtime.h>
#include <math.h>

// Problem constants (fixed by reference).
#define HIDDEN 1024
#define MEL    80
#define TSTEPS 1000
#define BATCH  64

// 64 persistent blocks (co-resident on 256 CUs), 512 threads = 8 waves.
// Wave w of block b owns hidden units b*16 + w*2 + {0,1}: lanes split as
// u=lane>>5 (unit), gate=(lane>>3)&3 (i,f,g,o), c8=lane&7 (128-col chunk).
// All 4 gates of a unit live in ONE wave -> gate nonlinearity is in-wave
// shuffles, no LDS round-trip, no second barrier.
#define NBLK 64
#define TPB  512

typedef unsigned long long ull;

// v_exp_f32-based activations (abs err ~1e-6 << 8.3e-4 threshold).
__device__ __forceinline__ float sigm_f(float x) { return 1.0f / (1.0f + __expf(-x)); }
__device__ __forceinline__ float tanh_f(float x) { return 1.0f - 2.0f / (1.0f + __expf(2.0f * x)); }

__global__ __launch_bounds__(TPB, 1) void tts_recur(   // (512,1): do NOT cap VGPRs —
    const float* __restrict__ dec_Wih,   // [4096, 80]   w[32] float4 must stay in regs
    const float* __restrict__ dec_Whh,   // [4096, 1024] (R2/R3 spilled at 84 VGPR!)
    const float* __restrict__ dec_bih,   // [4096]
    const float* __restrict__ dec_bhh,   // [4096]
    const float* __restrict__ lin_W,     // [80, 1024]
    const float* __restrict__ lin_b,     // [80]
    float* __restrict__ h_hist,          // [TSTEPS, 1024] (for epilogue, cached path)
    ull* __restrict__ hbuf)              // [2, 1024] packed {tag:32|float:32} exchange
{
    const int tid  = threadIdx.x;
    const int blk  = blockIdx.x;
    const int wv   = tid >> 6;
    const int lane = tid & 63;
    const int u    = lane >> 5;
    const int gate = (lane >> 3) & 3;
    const int c8   = lane & 7;
    const int unit_g = blk * 16 + wv * 2 + u;           // global hidden unit
    const int row_g  = gate * HIDDEN + unit_g;          // global gate row

    // Double-buffered skewed h tile: logical float i -> physical i + 4*(i>>7)
    // (row pitch 132). Chunk c8 starts at bank 4*c8, so the MAC's immediate-
    // offset ds_read_b128 stream covers all 32 banks -> conflict-free.
    __shared__ __align__(16) float h_s[2][8 * 132];

    // ---- one-time fold: w[k] = Whh_row + Wih_row @ lin_W (fp32, REGISTERS) ----
    const float* wih = dec_Wih + (size_t)row_g * MEL;
    const float* whh = dec_Whh + (size_t)row_g * HIDDEN;
    float4 w[32];
#pragma unroll
    for (int k = 0; k < 32; ++k) {
        const int col = c8 * 128 + k * 4;
        float4 a = *(const float4*)(whh + col);
        for (int m = 0; m < MEL; ++m) {
            const float aw = wih[m];
            const float4 lw = *(const float4*)(lin_W + (size_t)m * HIDDEN + col);
            a.x = fmaf(aw, lw.x, a.x);
            a.y = fmaf(aw, lw.y, a.y);
            a.z = fmaf(aw, lw.z, a.z);
            a.w = fmaf(aw, lw.w, a.w);
        }
        w[k] = a;
    }
    const float b_dec_r = dec_bih[row_g] + dec_bhh[row_g];   // step 0 (x=0, no lin_b)
    float b_comb_r = b_dec_r;                                // steps >= 1
    for (int m = 0; m < MEL; ++m)
        b_comb_r = fmaf(wih[m], lin_b[m], b_comb_r);

    float c_prev = 0.0f;   // cell state, replicated across the unit's 32 lanes
    for (int t = 0; t < TSTEPS; ++t) {
        float g;
        if (t == 0) {
            g = b_dec_r;                                     // h=c=x=0 -> g = b_dec
        } else {
            const int buf = t & 1;
            // Poll h[t-1]: 128 threads own 8 strided slots each (tag==t valid).
            // Tag travels with the value -> no fences/cache ops anywhere.
            if (tid < 128) {
                const ull* src = hbuf + ((t - 1) & 1) * HIDDEN;
                const unsigned tag = (unsigned)t;
                ull v[8];
#pragma unroll
                for (int j = 0; j < 8; ++j)
                    v[j] = __hip_atomic_load(src + tid + 128 * j,
                                             __ATOMIC_RELAXED, __HIP_MEMORY_SCOPE_SYSTEM);
#pragma unroll
                for (int j = 0; j < 8; ++j) {
                    while ((unsigned)(v[j] >> 32) != tag)
                        v[j] = __hip_atomic_load(src + tid + 128 * j,
                                                 __ATOMIC_RELAXED, __HIP_MEMORY_SCOPE_SYSTEM);
                    // logical index tid+128j -> physical tid+132j (stride-1 per wave)
                    h_s[buf][tid + 132 * j] = __uint_as_float((unsigned)v[j]);
                }
            }
            __syncthreads();   // ONLY barrier per step (h_s double-buffer makes it safe)

            // MAC: 32 immediate-offset ds_read_b128 (skewed, conflict-free) + 128 fma.
            const float4* hs4 = (const float4*)(&h_s[buf][0] + c8 * 132);
            float acc = 0.0f;
#pragma unroll
            for (int k = 0; k < 32; ++k) {
                const float4 hv = hs4[k];
                acc = fmaf(w[k].x, hv.x, acc);
                acc = fmaf(w[k].y, hv.y, acc);
                acc = fmaf(w[k].z, hv.z, acc);
                acc = fmaf(w[k].w, hv.w, acc);
            }
            // Butterfly over the 8 c8-lanes: every lane gets its row's full sum.
            acc += __shfl_xor(acc, 1, 64);
            acc += __shfl_xor(acc, 2, 64);
            acc += __shfl_xor(acc, 4, 64);
            g = acc + b_comb_r;
        }

        // In-wave gate gather: lanes {base, base+8, base+16, base+24} hold i,f,g,o.
        const int base = (lane & 32) | c8;
        const float gi = __shfl(g, base, 64);
        const float gf = __shfl(g, base | 8, 64);
        const float gg = __shfl(g, base | 16, 64);
        const float go = __shfl(g, base | 24, 64);
        const float c  = sigm_f(gf) * c_prev + sigm_f(gi) * tanh_f(gg);
        const float h  = sigm_f(go) * tanh_f(c);
        c_prev = c;

        // Publish: one 8B atomic {tag=t+1, h} per unit (lanes 0 and 32 of each wave).
        if ((lane & 31) == 0) {
            const ull pk = ((ull)(unsigned)(t + 1) << 32) | (ull)__float_as_uint(h);
            __hip_atomic_store(hbuf + (t & 1) * HIDDEN + unit_g, pk,
                               __ATOMIC_RELAXED, __HIP_MEMORY_SCOPE_SYSTEM);
            h_hist[(size_t)t * HIDDEN + unit_g] = h;
        }
    }
}

// Epilogue: frame[t] = lin_W @ h[t] + lin_b, broadcast to 64 batch rows.
// Batch broadcast parallelized across the block (was a 64-iter serial loop).
__global__ __launch_bounds__(128) void tts_frames(
    const float* __restrict__ lin_W, const float* __restrict__ lin_b,
    const float* __restrict__ h_hist, float* __restrict__ out)
{
    const int t = blockIdx.x;
    const int tid = threadIdx.x;
    __shared__ __align__(16) float h_sh[HIDDEN];
    __shared__ float f_s[MEL];
    const float4* src = (const float4*)(h_hist + (size_t)t * HIDDEN);
    ((float4*)h_sh)[tid] = src[tid];
    ((float4*)h_sh)[tid + 128] = src[tid + 128];
    __syncthreads();
    if (tid < MEL) {
        const float* wrow = lin_W + (size_t)tid * HIDDEN;
        float acc = lin_b[tid];
#pragma unroll 8
        for (int c = 0; c < HIDDEN; ++c)
            acc = fmaf(wrow[c], h_sh[c], acc);
        f_s[tid] = acc;
    }
    __syncthreads();
    for (int idx = tid; idx < BATCH * MEL; idx += 128) {
        const int b = idx / MEL;
        const int m = idx - b * MEL;
        out[(size_t)b * TSTEPS * MEL + (size_t)t * MEL + m] = f_s[m];
    }
}

extern "C" void kernel_launch(void* const* d_in, const int* in_sizes, int n_in,
                              void* d_out, int out_size, void* d_ws, size_t ws_size,
                              hipStream_t stream) {
    // Inputs: 0 text, 1 text_lens, 2 max_audio_len, 3 W_emb, 4..7 enc_*,
    // 8..11 dec_{Wih,Whh,bih,bhh}, 12 lin_W, 13 lin_b. Encoder is dead code:
    // enc_out never feeds the output; decoder input chain is self-contained.
    const float* dec_Wih = (const float*)d_in[8];
    const float* dec_Whh = (const float*)d_in[9];
    const float* dec_bih = (const float*)d_in[10];
    const float* dec_bhh = (const float*)d_in[11];
    const float* lin_W   = (const float*)d_in[12];
    const float* lin_b   = (const float*)d_in[13];
    float* out = (float*)d_out;

    // Workspace: h_hist fp32 [1000][1024] (4,096,000 B) + hbuf [2][1024] ull (16 KB).
    // 0xAA poison -> tag 0xAAAAAAAA never matches 1..1000, so no init pass needed.
    float* h_hist = (float*)d_ws;
    ull* hbuf = (ull*)((char*)d_ws + (size_t)TSTEPS * HIDDEN * sizeof(float));

    hipLaunchKernelGGL(tts_recur, dim3(NBLK), dim3(TPB), 0, stream,
                       dec_Wih, dec_Whh, dec_bih, dec_bhh, lin_W, lin_b, h_hist, hbuf);
    hipLaunchKernelGGL(tts_frames, dim3(TSTEPS), dim3(128), 0, stream,
                       lin_W, lin_b, h_hist, out);
}

// Round 5
// 4131.187 us; speedup vs baseline: 1.3196x; 1.2556x over previous
//
#include <hip/hip_runtime.h>
#include <math.h>

// Problem constants (fixed by reference).
#define HIDDEN 1024
#define MEL    80
#define TSTEPS 1000
#define BATCH  64

// 64 persistent blocks (co-resident on 256 CUs), 512 threads = 8 waves.
// Wave w of block b owns hidden units b*16 + w*2 + {0,1}: lanes split as
// u=lane>>5 (unit), gate=(lane>>3)&3 (i,f,g,o), c8=lane&7 (128-col chunk).
#define NBLK 64
#define TPB  512

typedef unsigned long long ull;

// v_exp_f32-based activations (abs err ~1e-6 << 8.3e-4 threshold).
__device__ __forceinline__ float sigm_f(float x) { return 1.0f / (1.0f + __expf(-x)); }
__device__ __forceinline__ float tanh_f(float x) { return 1.0f - 2.0f / (1.0f + __expf(2.0f * x)); }

__global__ __launch_bounds__(TPB, 1) void tts_recur(
    const float* __restrict__ dec_Wih,   // [4096, 80]
    const float* __restrict__ dec_Whh,   // [4096, 1024]
    const float* __restrict__ dec_bih,   // [4096]
    const float* __restrict__ dec_bhh,   // [4096]
    const float* __restrict__ lin_W,     // [80, 1024]
    const float* __restrict__ lin_b,     // [80]
    float* __restrict__ h_hist,          // [TSTEPS, 1024] (for epilogue)
    ull* __restrict__ hbuf)              // [2, 1024] packed {tag:32|float:32}
{
    const int tid  = threadIdx.x;
    const int blk  = blockIdx.x;
    const int wv   = tid >> 6;
    const int lane = tid & 63;
    const int u    = lane >> 5;
    const int gate = (lane >> 3) & 3;
    const int c8   = lane & 7;
    const int unit_g = blk * 16 + wv * 2 + u;
    const int row_g  = gate * HIDDEN + unit_g;

    // Double-buffered skewed h tile: logical i -> physical i + 4*(i>>7)
    // (pitch 132 floats). Chunk c8 starts at bank 4*c8 -> the MAC's
    // immediate-offset ds_read_b128 stream is conflict-free (verified R4: 0).
    __shared__ __align__(16) float h_s[2][8 * 132];

    // ---- one-time fold: w = Whh_row + Wih_row @ lin_W, in REGISTERS ----
    // CRITICAL STRUCTURE (R2-R4 bug): the k-loop must be INNERMOST so
    // "#pragma unroll" actually fully unrolls it and w[] is SROA'd into
    // VGPRs. With k outermost (inner m-loop), LLVM refuses the full unroll
    // and w[] lives in scratch -> 32 L2-latency reloads inside the hot MAC
    // loop every step (the invariant ~5 us/step of R2-R4).
    const float* wih = dec_Wih + (size_t)row_g * MEL;
    const float* whh = dec_Whh + (size_t)row_g * HIDDEN + c8 * 128;
    float4 w[32];
#pragma unroll
    for (int k = 0; k < 32; ++k)
        w[k] = *(const float4*)(whh + k * 4);
#pragma unroll 1
    for (int m = 0; m < MEL; ++m) {
        const float aw = wih[m];
        const float4* lw4 = (const float4*)(lin_W + (size_t)m * HIDDEN + c8 * 128);
#pragma unroll
        for (int k = 0; k < 32; ++k) {
            const float4 lw = lw4[k];
            w[k].x = fmaf(aw, lw.x, w[k].x);
            w[k].y = fmaf(aw, lw.y, w[k].y);
            w[k].z = fmaf(aw, lw.z, w[k].z);
            w[k].w = fmaf(aw, lw.w, w[k].w);
        }
    }
    const float b_dec_r = dec_bih[row_g] + dec_bhh[row_g];   // step 0 (x=0)
    float b_comb_r = b_dec_r;                                // steps >= 1
    for (int m = 0; m < MEL; ++m)
        b_comb_r = fmaf(wih[m], lin_b[m], b_comb_r);

    float c_prev = 0.0f;   // cell state, replicated across the unit's 32 lanes
    for (int t = 0; t < TSTEPS; ++t) {
        float g;
        if (t == 0) {
            g = b_dec_r;                                     // h=c=x=0 -> g = b_dec
        } else {
            const int buf = t & 1;
            // Poll h[t-1]: every thread owns 2 adjacent slots (tag==t valid).
            // Tag travels with the value (8B atomic) -> no fences, no cache ops.
            {
                const ull* src = hbuf + ((t - 1) & 1) * HIDDEN;
                const unsigned tag = (unsigned)t;
                const int i0 = 2 * tid;
                ull v0 = __hip_atomic_load(src + i0,     __ATOMIC_RELAXED, __HIP_MEMORY_SCOPE_SYSTEM);
                ull v1 = __hip_atomic_load(src + i0 + 1, __ATOMIC_RELAXED, __HIP_MEMORY_SCOPE_SYSTEM);
                while ((unsigned)(v0 >> 32) != tag) {
                    __builtin_amdgcn_s_sleep(1);
                    v0 = __hip_atomic_load(src + i0, __ATOMIC_RELAXED, __HIP_MEMORY_SCOPE_SYSTEM);
                }
                while ((unsigned)(v1 >> 32) != tag) {
                    __builtin_amdgcn_s_sleep(1);
                    v1 = __hip_atomic_load(src + i0 + 1, __ATOMIC_RELAXED, __HIP_MEMORY_SCOPE_SYSTEM);
                }
                const int p = i0 + 4 * (i0 >> 7);   // i0,i0+1 in same chunk -> adjacent
                h_s[buf][p]     = __uint_as_float((unsigned)v0);
                h_s[buf][p + 1] = __uint_as_float((unsigned)v1);
            }
            __syncthreads();   // only barrier per step (double-buffer proof in R4 notes)

            // MAC: 32 immediate-offset ds_read_b128 + 128 fma, 4 split accumulators.
            const float4* hs4 = (const float4*)(&h_s[buf][0] + c8 * 132);
            float a0 = 0.0f, a1 = 0.0f, a2 = 0.0f, a3 = 0.0f;
#pragma unroll
            for (int k = 0; k < 32; k += 4) {
                const float4 h0 = hs4[k], h1 = hs4[k + 1], h2 = hs4[k + 2], h3 = hs4[k + 3];
                a0 = fmaf(w[k].x, h0.x, a0); a0 = fmaf(w[k].y, h0.y, a0);
                a0 = fmaf(w[k].z, h0.z, a0); a0 = fmaf(w[k].w, h0.w, a0);
                a1 = fmaf(w[k+1].x, h1.x, a1); a1 = fmaf(w[k+1].y, h1.y, a1);
                a1 = fmaf(w[k+1].z, h1.z, a1); a1 = fmaf(w[k+1].w, h1.w, a1);
                a2 = fmaf(w[k+2].x, h2.x, a2); a2 = fmaf(w[k+2].y, h2.y, a2);
                a2 = fmaf(w[k+2].z, h2.z, a2); a2 = fmaf(w[k+2].w, h2.w, a2);
                a3 = fmaf(w[k+3].x, h3.x, a3); a3 = fmaf(w[k+3].y, h3.y, a3);
                a3 = fmaf(w[k+3].z, h3.z, a3); a3 = fmaf(w[k+3].w, h3.w, a3);
            }
            float acc = (a0 + a1) + (a2 + a3);
            // Butterfly over the 8 c8-lanes: every lane gets its row's full sum.
            acc += __shfl_xor(acc, 1, 64);
            acc += __shfl_xor(acc, 2, 64);
            acc += __shfl_xor(acc, 4, 64);
            g = acc + b_comb_r;
        }

        // In-wave gate gather: lanes {base, base+8, base+16, base+24} = i,f,g,o.
        const int base = (lane & 32) | c8;
        const float gi = __shfl(g, base, 64);
        const float gf = __shfl(g, base | 8, 64);
        const float gg = __shfl(g, base | 16, 64);
        const float go = __shfl(g, base | 24, 64);
        const float c  = sigm_f(gf) * c_prev + sigm_f(gi) * tanh_f(gg);
        const float h  = sigm_f(go) * tanh_f(c);
        c_prev = c;

        // Publish: one 8B atomic {tag=t+1, h} per unit (lanes 0 and 32).
        if ((lane & 31) == 0) {
            const ull pk = ((ull)(unsigned)(t + 1) << 32) | (ull)__float_as_uint(h);
            __hip_atomic_store(hbuf + (t & 1) * HIDDEN + unit_g, pk,
                               __ATOMIC_RELAXED, __HIP_MEMORY_SCOPE_SYSTEM);
            h_hist[(size_t)t * HIDDEN + unit_g] = h;
        }
    }
}

// Epilogue: frame[t] = lin_W @ h[t] + lin_b, broadcast to 64 batch rows.
__global__ __launch_bounds__(128) void tts_frames(
    const float* __restrict__ lin_W, const float* __restrict__ lin_b,
    const float* __restrict__ h_hist, float* __restrict__ out)
{
    const int t = blockIdx.x;
    const int tid = threadIdx.x;
    __shared__ __align__(16) float h_sh[HIDDEN];
    __shared__ float f_s[MEL];
    const float4* src = (const float4*)(h_hist + (size_t)t * HIDDEN);
    ((float4*)h_sh)[tid] = src[tid];
    ((float4*)h_sh)[tid + 128] = src[tid + 128];
    __syncthreads();
    if (tid < MEL) {
        const float* wrow = lin_W + (size_t)tid * HIDDEN;
        float acc = lin_b[tid];
#pragma unroll 8
        for (int c = 0; c < HIDDEN; ++c)
            acc = fmaf(wrow[c], h_sh[c], acc);
        f_s[tid] = acc;
    }
    __syncthreads();
    for (int idx = tid; idx < BATCH * MEL; idx += 128) {
        const int b = idx / MEL;
        const int m = idx - b * MEL;
        out[(size_t)b * TSTEPS * MEL + (size_t)t * MEL + m] = f_s[m];
    }
}

extern "C" void kernel_launch(void* const* d_in, const int* in_sizes, int n_in,
                              void* d_out, int out_size, void* d_ws, size_t ws_size,
                              hipStream_t stream) {
    // Inputs: 0 text, 1 text_lens, 2 max_audio_len, 3 W_emb, 4..7 enc_*,
    // 8..11 dec_{Wih,Whh,bih,bhh}, 12 lin_W, 13 lin_b. Encoder is dead code.
    const float* dec_Wih = (const float*)d_in[8];
    const float* dec_Whh = (const float*)d_in[9];
    const float* dec_bih = (const float*)d_in[10];
    const float* dec_bhh = (const float*)d_in[11];
    const float* lin_W   = (const float*)d_in[12];
    const float* lin_b   = (const float*)d_in[13];
    float* out = (float*)d_out;

    // Workspace: h_hist fp32 [1000][1024] (4,096,000 B) + hbuf [2][1024] ull (16 KB).
    // 0xAA poison -> tag 0xAAAAAAAA never matches 1..1000, so no init pass needed.
    float* h_hist = (float*)d_ws;
    ull* hbuf = (ull*)((char*)d_ws + (size_t)TSTEPS * HIDDEN * sizeof(float));

    hipLaunchKernelGGL(tts_recur, dim3(NBLK), dim3(TPB), 0, stream,
                       dec_Wih, dec_Whh, dec_bih, dec_bhh, lin_W, lin_b, h_hist, hbuf);
    hipLaunchKernelGGL(tts_frames, dim3(TSTEPS), dim3(128), 0, stream,
                       lin_W, lin_b, h_hist, out);
}

// Round 6
// 2392.107 us; speedup vs baseline: 2.2790x; 1.7270x over previous
//
#include <hip/hip_runtime.h>
#include <math.h>

// Problem constants (fixed by reference).
#define HIDDEN 1024
#define MEL    80
#define TSTEPS 1000
#define BATCH  64

// 64 persistent blocks x 1024 threads (16 waves). Block owns 16 hidden units
// = 64 gate rows. Wave wv owns column slice [wv*64, wv*64+64) for ALL 64
// rows; lane = gate row (gate = lane>>4, unit jj = lane&15). Per-thread
// folded weights: 16 float4 = 64 VGPRs -> fits the 128-reg cap that
// 16 waves/CU requires (R2-R5 bug: 128 floats/thread + load clusters
// > 256 regs -> allocator spilled w[] to scratch in every variant).
#define NBLK 64
#define TPB  1024

typedef unsigned long long ull;

// v_exp_f32-based activations (abs err ~1e-6 << 8.3e-4 threshold).
__device__ __forceinline__ float sigm_f(float x) { return 1.0f / (1.0f + __expf(-x)); }
__device__ __forceinline__ float tanh_f(float x) { return 1.0f - 2.0f / (1.0f + __expf(2.0f * x)); }

__global__ __launch_bounds__(TPB, 4) void tts_recur(
    const float* __restrict__ dec_Wih,   // [4096, 80]
    const float* __restrict__ dec_Whh,   // [4096, 1024]
    const float* __restrict__ dec_bih,   // [4096]
    const float* __restrict__ dec_bhh,   // [4096]
    const float* __restrict__ lin_W,     // [80, 1024]
    const float* __restrict__ lin_b,     // [80]
    float* __restrict__ h_hist,          // [TSTEPS, 1024] (for epilogue)
    ull* __restrict__ hbuf)              // [2, 1024] packed {tag:32|float:32}
{
    const int tid  = threadIdx.x;
    const int blk  = blockIdx.x;
    const int wv   = tid >> 6;           // 0..15: column slice
    const int lane = tid & 63;           // gate row within block
    const int jj   = lane & 15;          // unit within block
    const int gate = lane >> 4;          // i,f,g,o
    const int unit_g = blk * 16 + jj;
    const int row_g  = gate * HIDDEN + unit_g;

    __shared__ __align__(16) float h_s[2][HIDDEN];   // double-buffered h
    __shared__ float part[2][64 * 17];               // partials, pitch 17 (2-way only)

    // ---- one-time fold: w = Whh_row_slice + Wih_row @ lin_W_slice (regs) ----
    const float* wih = dec_Wih + (size_t)row_g * MEL;
    const float* whh = dec_Whh + (size_t)row_g * HIDDEN + wv * 64;
    float4 w[16];
#pragma unroll
    for (int k = 0; k < 16; ++k)
        w[k] = *(const float4*)(whh + k * 4);
#pragma unroll 1
    for (int m = 0; m < MEL; ++m) {
        const float aw = wih[m];
        const float4* lw4 = (const float4*)(lin_W + (size_t)m * HIDDEN + wv * 64);
        // two chunks of 8 to cap in-flight load registers (stay under 128)
#pragma unroll
        for (int k = 0; k < 8; ++k) {
            const float4 lw = lw4[k];
            w[k].x = fmaf(aw, lw.x, w[k].x); w[k].y = fmaf(aw, lw.y, w[k].y);
            w[k].z = fmaf(aw, lw.z, w[k].z); w[k].w = fmaf(aw, lw.w, w[k].w);
        }
#pragma unroll
        for (int k = 8; k < 16; ++k) {
            const float4 lw = lw4[k];
            w[k].x = fmaf(aw, lw.x, w[k].x); w[k].y = fmaf(aw, lw.y, w[k].y);
            w[k].z = fmaf(aw, lw.z, w[k].z); w[k].w = fmaf(aw, lw.w, w[k].w);
        }
    }
    float b_comb_r = dec_bih[row_g] + dec_bhh[row_g];
    const float b_dec_r = b_comb_r;                  // step 0 (x=0, no lin_b fold)
    for (int m = 0; m < MEL; ++m)
        b_comb_r = fmaf(wih[m], lin_b[m], b_comb_r);

    float c_prev = 0.0f;                             // live on wave 0 lanes

    // ---- step 0: g = b_dec (h=c=x=0); wave 0 only ----
    if (wv == 0) {
        const float g = b_dec_r;
        const float gi = __shfl(g, jj, 64);
        const float gf = __shfl(g, 16 + jj, 64); (void)gf;   // f*c0 = 0
        const float gg = __shfl(g, 32 + jj, 64);
        const float go = __shfl(g, 48 + jj, 64);
        const float c  = sigm_f(gi) * tanh_f(gg);
        const float h  = sigm_f(go) * tanh_f(c);
        c_prev = c;
        if (lane < 16) {
            const ull pk = ((ull)1u << 32) | (ull)__float_as_uint(h);
            __hip_atomic_store(hbuf + unit_g, pk,
                               __ATOMIC_RELAXED, __HIP_MEMORY_SCOPE_SYSTEM);
            h_hist[unit_g] = h;
        }
    }

    // ---- steps 1..TSTEPS-1 ----
    for (int t = 1; t < TSTEPS; ++t) {
        const int buf = t & 1;
        // Poll h[t-1]: exactly one slot per thread (tag==t valid). Tag travels
        // with the value in one 8B atomic -> no fences, no cache maintenance.
        {
            const ull* src = hbuf + ((t - 1) & 1) * HIDDEN;
            ull v = __hip_atomic_load(src + tid, __ATOMIC_RELAXED, __HIP_MEMORY_SCOPE_SYSTEM);
            while ((unsigned)(v >> 32) != (unsigned)t) {
                __builtin_amdgcn_s_sleep(1);
                v = __hip_atomic_load(src + tid, __ATOMIC_RELAXED, __HIP_MEMORY_SCOPE_SYSTEM);
            }
            h_s[buf][tid] = __uint_as_float((unsigned)v);
        }
        __syncthreads();                               // barrier A

        // Broadcast MAC: 16 uniform-address ds_read_b128 (all lanes read the
        // SAME h chunk -> LDS broadcast, zero conflicts), 64 fma into 4 accs.
        const float4* hp = (const float4*)(&h_s[buf][wv * 64]);
        float a0 = 0.f, a1 = 0.f, a2 = 0.f, a3 = 0.f;
#pragma unroll
        for (int k = 0; k < 16; k += 4) {
            const float4 h0 = hp[k], h1 = hp[k + 1], h2 = hp[k + 2], h3 = hp[k + 3];
            a0 = fmaf(w[k].x, h0.x, a0);   a0 = fmaf(w[k].y, h0.y, a0);
            a0 = fmaf(w[k].z, h0.z, a0);   a0 = fmaf(w[k].w, h0.w, a0);
            a1 = fmaf(w[k+1].x, h1.x, a1); a1 = fmaf(w[k+1].y, h1.y, a1);
            a1 = fmaf(w[k+1].z, h1.z, a1); a1 = fmaf(w[k+1].w, h1.w, a1);
            a2 = fmaf(w[k+2].x, h2.x, a2); a2 = fmaf(w[k+2].y, h2.y, a2);
            a2 = fmaf(w[k+2].z, h2.z, a2); a2 = fmaf(w[k+2].w, h2.w, a2);
            a3 = fmaf(w[k+3].x, h3.x, a3); a3 = fmaf(w[k+3].y, h3.y, a3);
            a3 = fmaf(w[k+3].z, h3.z, a3); a3 = fmaf(w[k+3].w, h3.w, a3);
        }
        part[buf][lane * 17 + wv] = (a0 + a1) + (a2 + a3);
        __syncthreads();                               // barrier B

        if (wv == 0) {
            // Reduce 16 partials for this lane's row, then in-wave gates.
            const float* pr = &part[buf][lane * 17];
            float p[16];
#pragma unroll
            for (int i = 0; i < 16; ++i) p[i] = pr[i];
            const float s = (((p[0]+p[1])+(p[2]+p[3])) + ((p[4]+p[5])+(p[6]+p[7])))
                          + (((p[8]+p[9])+(p[10]+p[11])) + ((p[12]+p[13])+(p[14]+p[15])));
            const float g = s + b_comb_r;
            const float gi = __shfl(g, jj, 64);
            const float gf = __shfl(g, 16 + jj, 64);
            const float gg = __shfl(g, 32 + jj, 64);
            const float go = __shfl(g, 48 + jj, 64);
            const float c  = sigm_f(gf) * c_prev + sigm_f(gi) * tanh_f(gg);
            const float h  = sigm_f(go) * tanh_f(c);
            c_prev = c;
            if (lane < 16) {
                const ull pk = ((ull)(unsigned)(t + 1) << 32) | (ull)__float_as_uint(h);
                __hip_atomic_store(hbuf + buf * HIDDEN + unit_g, pk,
                                   __ATOMIC_RELAXED, __HIP_MEMORY_SCOPE_SYSTEM);
                h_hist[(size_t)t * HIDDEN + unit_g] = h;
            }
        }
        // Safety of racing ahead: other waves' next-step writes touch
        // h_s[buf^1] (double-buffered) and part[buf^1] only after barrier
        // A(t+1), which wave 0 joins only after its part[buf] reads. hbuf
        // overwrite safety: h(t) lands only after all blocks consumed h(t-1),
        // which required h(t-2) fully consumed everywhere (R4 proof).
    }
}

// Epilogue: frame[t] = lin_W @ h[t] + lin_b, broadcast to 64 batch rows.
__global__ __launch_bounds__(128) void tts_frames(
    const float* __restrict__ lin_W, const float* __restrict__ lin_b,
    const float* __restrict__ h_hist, float* __restrict__ out)
{
    const int t = blockIdx.x;
    const int tid = threadIdx.x;
    __shared__ __align__(16) float h_sh[HIDDEN];
    __shared__ float f_s[MEL];
    const float4* src = (const float4*)(h_hist + (size_t)t * HIDDEN);
    ((float4*)h_sh)[tid] = src[tid];
    ((float4*)h_sh)[tid + 128] = src[tid + 128];
    __syncthreads();
    if (tid < MEL) {
        const float* wrow = lin_W + (size_t)tid * HIDDEN;
        float acc = lin_b[tid];
#pragma unroll 8
        for (int c = 0; c < HIDDEN; ++c)
            acc = fmaf(wrow[c], h_sh[c], acc);
        f_s[tid] = acc;
    }
    __syncthreads();
    for (int idx = tid; idx < BATCH * MEL; idx += 128) {
        const int b = idx / MEL;
        const int m = idx - b * MEL;
        out[(size_t)b * TSTEPS * MEL + (size_t)t * MEL + m] = f_s[m];
    }
}

extern "C" void kernel_launch(void* const* d_in, const int* in_sizes, int n_in,
                              void* d_out, int out_size, void* d_ws, size_t ws_size,
                              hipStream_t stream) {
    // Inputs: 0 text, 1 text_lens, 2 max_audio_len, 3 W_emb, 4..7 enc_*,
    // 8..11 dec_{Wih,Whh,bih,bhh}, 12 lin_W, 13 lin_b. Encoder is dead code.
    const float* dec_Wih = (const float*)d_in[8];
    const float* dec_Whh = (const float*)d_in[9];
    const float* dec_bih = (const float*)d_in[10];
    const float* dec_bhh = (const float*)d_in[11];
    const float* lin_W   = (const float*)d_in[12];
    const float* lin_b   = (const float*)d_in[13];
    float* out = (float*)d_out;

    // Workspace: h_hist fp32 [1000][1024] (4,096,000 B) + hbuf [2][1024] ull.
    // 0xAA poison -> tag 0xAAAAAAAA never matches 1..1000, so no init pass.
    float* h_hist = (float*)d_ws;
    ull* hbuf = (ull*)((char*)d_ws + (size_t)TSTEPS * HIDDEN * sizeof(float));

    hipLaunchKernelGGL(tts_recur, dim3(NBLK), dim3(TPB), 0, stream,
                       dec_Wih, dec_Whh, dec_bih, dec_bhh, lin_W, lin_b, h_hist, hbuf);
    hipLaunchKernelGGL(tts_frames, dim3(TSTEPS), dim3(128), 0, stream,
                       lin_W, lin_b, h_hist, out);
}

// Round 7
// 2186.957 us; speedup vs baseline: 2.4928x; 1.0938x over previous
//
#include <hip/hip_runtime.h>
#include <math.h>

// Problem constants (fixed by reference).
#define HIDDEN 1024
#define MEL    80
#define TSTEPS 1000
#define BATCH  64

// 64 persistent blocks x 1024 threads (16 waves). Block owns 16 hidden units
// = 64 gate rows. Wave wv owns column slice [wv*64, wv*64+64) for ALL 64
// rows; lane = gate row in MAC phase, and lane = column (slot 64*wv+lane)
// in the poll phase. KEY (R7): a wave's MAC needs ONLY the 64 h values its
// own lanes poll -> no block barrier between poll and MAC. Waves run
// decoupled; the single per-step __syncthreads (B) sits before wave0's
// cross-wave reduction.
#define NBLK 64
#define TPB  1024

typedef unsigned long long ull;

// v_exp_f32-based activations (abs err ~1e-6 << 8.3e-4 threshold).
__device__ __forceinline__ float sigm_f(float x) { return 1.0f / (1.0f + __expf(-x)); }
__device__ __forceinline__ float tanh_f(float x) { return 1.0f - 2.0f / (1.0f + __expf(2.0f * x)); }

__global__ __launch_bounds__(TPB, 4) void tts_recur(
    const float* __restrict__ dec_Wih,   // [4096, 80]
    const float* __restrict__ dec_Whh,   // [4096, 1024]
    const float* __restrict__ dec_bih,   // [4096]
    const float* __restrict__ dec_bhh,   // [4096]
    const float* __restrict__ lin_W,     // [80, 1024]
    const float* __restrict__ lin_b,     // [80]
    float* __restrict__ h_hist,          // [TSTEPS, 1024] (for epilogue)
    ull* __restrict__ hbuf)              // [2, 1024] packed {tag:32|float:32}
{
    const int tid  = threadIdx.x;
    const int blk  = blockIdx.x;
    const int wv   = tid >> 6;           // 0..15: column slice / slot chunk
    const int lane = tid & 63;           // gate row (MAC) / column (poll)
    const int jj   = lane & 15;          // unit within block
    const int gate = lane >> 4;          // i,f,g,o
    const int unit_g = blk * 16 + jj;
    const int row_g  = gate * HIDDEN + unit_g;

    // Producer wave gets issue priority over the 15 spinning consumer waves.
    if (wv == 0) __builtin_amdgcn_s_setprio(3);

    __shared__ __align__(16) float hEx[16][64];   // per-wave h slice (single buffer:
                                                  // wave-private, write-after-read in
                                                  // program order -> no race)
    __shared__ float part[2][64 * 17];            // partials, pitch 17 (2-way = free)

    // ---- one-time fold: w = Whh_row_slice + Wih_row @ lin_W_slice (regs) ----
    const float* wih = dec_Wih + (size_t)row_g * MEL;
    const float* whh = dec_Whh + (size_t)row_g * HIDDEN + wv * 64;
    float4 w[16];
#pragma unroll
    for (int k = 0; k < 16; ++k)
        w[k] = *(const float4*)(whh + k * 4);
#pragma unroll 1
    for (int m = 0; m < MEL; ++m) {
        const float aw = wih[m];
        const float4* lw4 = (const float4*)(lin_W + (size_t)m * HIDDEN + wv * 64);
#pragma unroll
        for (int k = 0; k < 8; ++k) {
            const float4 lw = lw4[k];
            w[k].x = fmaf(aw, lw.x, w[k].x); w[k].y = fmaf(aw, lw.y, w[k].y);
            w[k].z = fmaf(aw, lw.z, w[k].z); w[k].w = fmaf(aw, lw.w, w[k].w);
        }
#pragma unroll
        for (int k = 8; k < 16; ++k) {
            const float4 lw = lw4[k];
            w[k].x = fmaf(aw, lw.x, w[k].x); w[k].y = fmaf(aw, lw.y, w[k].y);
            w[k].z = fmaf(aw, lw.z, w[k].z); w[k].w = fmaf(aw, lw.w, w[k].w);
        }
    }
    float b_comb_r = dec_bih[row_g] + dec_bhh[row_g];
    const float b_dec_r = b_comb_r;                  // step 0 (x=0, no lin_b fold)
    for (int m = 0; m < MEL; ++m)
        b_comb_r = fmaf(wih[m], lin_b[m], b_comb_r);

    float c_prev = 0.0f;                             // live on wave 0 lanes

    // ---- step 0: g = b_dec (h=c=x=0); wave 0 only ----
    if (wv == 0) {
        const float g = b_dec_r;
        const float gi = __shfl(g, jj, 64);
        const float gg = __shfl(g, 32 + jj, 64);
        const float go = __shfl(g, 48 + jj, 64);
        const float c  = sigm_f(gi) * tanh_f(gg);    // f-gate * c0 = 0
        const float h  = sigm_f(go) * tanh_f(c);
        c_prev = c;
        if (lane < 16) {
            const ull pk = ((ull)1u << 32) | (ull)__float_as_uint(h);
            __hip_atomic_store(hbuf + unit_g, pk,
                               __ATOMIC_RELAXED, __HIP_MEMORY_SCOPE_SYSTEM);
            h_hist[unit_g] = h;
        }
    }

    // ---- steps 1..TSTEPS-1 ----
    for (int t = 1; t < TSTEPS; ++t) {
        const int buf = t & 1;
        // Poll own slot (tag==t valid). Tag travels with the value in one 8B
        // atomic -> no fences, no cache maintenance. No s_sleep: detection
        // granularity = load latency; sleep only added to it.
        {
            const ull* src = hbuf + ((t - 1) & 1) * HIDDEN;
            ull v = __hip_atomic_load(src + tid, __ATOMIC_RELAXED, __HIP_MEMORY_SCOPE_SYSTEM);
            while ((unsigned)(v >> 32) != (unsigned)t)
                v = __hip_atomic_load(src + tid, __ATOMIC_RELAXED, __HIP_MEMORY_SCOPE_SYSTEM);
            hEx[wv][lane] = __uint_as_float((unsigned)v);
        }
        // Wave-local exchange: per-wave DS ops execute in program order (HW);
        // wave_barrier stops compiler reordering (rocPRIM warp-exchange idiom).
        __builtin_amdgcn_wave_barrier();

        // Broadcast MAC: 16 uniform-address ds_read_b128 (LDS broadcast, zero
        // conflicts) + 64 fma into 4 accumulators. No block barrier needed.
        const float4* hp = (const float4*)&hEx[wv][0];
        float a0 = 0.f, a1 = 0.f, a2 = 0.f, a3 = 0.f;
#pragma unroll
        for (int k = 0; k < 16; k += 4) {
            const float4 h0 = hp[k], h1 = hp[k + 1], h2 = hp[k + 2], h3 = hp[k + 3];
            a0 = fmaf(w[k].x, h0.x, a0);   a0 = fmaf(w[k].y, h0.y, a0);
            a0 = fmaf(w[k].z, h0.z, a0);   a0 = fmaf(w[k].w, h0.w, a0);
            a1 = fmaf(w[k+1].x, h1.x, a1); a1 = fmaf(w[k+1].y, h1.y, a1);
            a1 = fmaf(w[k+1].z, h1.z, a1); a1 = fmaf(w[k+1].w, h1.w, a1);
            a2 = fmaf(w[k+2].x, h2.x, a2); a2 = fmaf(w[k+2].y, h2.y, a2);
            a2 = fmaf(w[k+2].z, h2.z, a2); a2 = fmaf(w[k+2].w, h2.w, a2);
            a3 = fmaf(w[k+3].x, h3.x, a3); a3 = fmaf(w[k+3].y, h3.y, a3);
            a3 = fmaf(w[k+3].z, h3.z, a3); a3 = fmaf(w[k+3].w, h3.w, a3);
        }
        part[buf][lane * 17 + wv] = (a0 + a1) + (a2 + a3);
        __syncthreads();                               // barrier B (only one/step)

        if (wv == 0) {
            // Reduce 16 partials for this lane's row, then in-wave gates.
            const float* pr = &part[buf][lane * 17];
            float p[16];
#pragma unroll
            for (int i = 0; i < 16; ++i) p[i] = pr[i];
            const float s = (((p[0]+p[1])+(p[2]+p[3])) + ((p[4]+p[5])+(p[6]+p[7])))
                          + (((p[8]+p[9])+(p[10]+p[11])) + ((p[12]+p[13])+(p[14]+p[15])));
            const float g = s + b_comb_r;
            const float gi = __shfl(g, jj, 64);
            const float gf = __shfl(g, 16 + jj, 64);
            const float gg = __shfl(g, 32 + jj, 64);
            const float go = __shfl(g, 48 + jj, 64);
            const float c  = sigm_f(gf) * c_prev + sigm_f(gi) * tanh_f(gg);
            const float h  = sigm_f(go) * tanh_f(c);
            c_prev = c;
            if (lane < 16) {
                const ull pk = ((ull)(unsigned)(t + 1) << 32) | (ull)__float_as_uint(h);
                __hip_atomic_store(hbuf + buf * HIDDEN + unit_g, pk,
                                   __ATOMIC_RELAXED, __HIP_MEMORY_SCOPE_SYSTEM);
                h_hist[(size_t)t * HIDDEN + unit_g] = h;
            }
        }
        // Race-freedom: part is double-buffered; waves write part[buf^1](t+1)
        // only before barrier B(t+1), which wave0 joins after its part[buf](t)
        // reads. hEx is wave-private with program-order write-after-read.
        // hbuf overwrite (h(t) over h(t-2)): P publishes h(t) only after
        // barrier B(t) <- P observed ALL tags t <- every block Q published
        // h(t-1) <- Q's barrier B(t-1) <- Q fully consumed h(t-2). QED.
    }
}

// Epilogue: frame[t] = lin_W @ h[t] + lin_b, broadcast to 64 batch rows.
__global__ __launch_bounds__(128) void tts_frames(
    const float* __restrict__ lin_W, const float* __restrict__ lin_b,
    const float* __restrict__ h_hist, float* __restrict__ out)
{
    const int t = blockIdx.x;
    const int tid = threadIdx.x;
    __shared__ __align__(16) float h_sh[HIDDEN];
    __shared__ float f_s[MEL];
    const float4* src = (const float4*)(h_hist + (size_t)t * HIDDEN);
    ((float4*)h_sh)[tid] = src[tid];
    ((float4*)h_sh)[tid + 128] = src[tid + 128];
    __syncthreads();
    if (tid < MEL) {
        const float* wrow = lin_W + (size_t)tid * HIDDEN;
        float acc = lin_b[tid];
#pragma unroll 8
        for (int c = 0; c < HIDDEN; ++c)
            acc = fmaf(wrow[c], h_sh[c], acc);
        f_s[tid] = acc;
    }
    __syncthreads();
    for (int idx = tid; idx < BATCH * MEL; idx += 128) {
        const int b = idx / MEL;
        const int m = idx - b * MEL;
        out[(size_t)b * TSTEPS * MEL + (size_t)t * MEL + m] = f_s[m];
    }
}

extern "C" void kernel_launch(void* const* d_in, const int* in_sizes, int n_in,
                              void* d_out, int out_size, void* d_ws, size_t ws_size,
                              hipStream_t stream) {
    // Inputs: 0 text, 1 text_lens, 2 max_audio_len, 3 W_emb, 4..7 enc_*,
    // 8..11 dec_{Wih,Whh,bih,bhh}, 12 lin_W, 13 lin_b. Encoder is dead code.
    const float* dec_Wih = (const float*)d_in[8];
    const float* dec_Whh = (const float*)d_in[9];
    const float* dec_bih = (const float*)d_in[10];
    const float* dec_bhh = (const float*)d_in[11];
    const float* lin_W   = (const float*)d_in[12];
    const float* lin_b   = (const float*)d_in[13];
    float* out = (float*)d_out;

    // Workspace: h_hist fp32 [1000][1024] (4,096,000 B) + hbuf [2][1024] ull.
    // 0xAA poison -> tag 0xAAAAAAAA never matches 1..1000, so no init pass.
    float* h_hist = (float*)d_ws;
    ull* hbuf = (ull*)((char*)d_ws + (size_t)TSTEPS * HIDDEN * sizeof(float));

    hipLaunchKernelGGL(tts_recur, dim3(NBLK), dim3(TPB), 0, stream,
                       dec_Wih, dec_Whh, dec_bih, dec_bhh, lin_W, lin_b, h_hist, hbuf);
    hipLaunchKernelGGL(tts_frames, dim3(TSTEPS), dim3(128), 0, stream,
                       lin_W, lin_b, h_hist, out);
}